// Round 5
// baseline (130.997 us; speedup 1.0000x reference)
//
#include <hip/hip_runtime.h>
#include <math.h>

#define NPTS   2048
#define BD     512                 // 8 waves -> 2 waves/SIMD on the CU
#define PPT    (NPTS / BD)         // 4 points per thread
#define NMOM   72
#define NITERS 10
#define DAMPF  1e-8f

__device__ __forceinline__ float frcp(float x) { return __builtin_amdgcn_rcpf(x); }
__device__ __forceinline__ float frsq(float x) { return __builtin_amdgcn_rsqf(x); }

// ---------------------------------------------------------------------------
// Fully fused, one 512-thread block per batch (grid = 256 = 1 block/CU).
//  Phase A: 4 pts/thread moments (unroll 2 -> ~26 loads in flight/round,
//           8 waves/CU for TLP; r2's fused had only 4 waves/CU total).
//  Phase B: wave-butterfly reduction: 5 shfl_xor stages within 32-lane
//           groups -> 16 partials/moment -> LDS [16][73] -> 72-thread combine.
//           Replaces the 74KB LDS transpose + 36-lane serial tail (~3000 cy)
//           with ~800 VALU ops, fully parallel.
//  Phase C: thread 0 fast-math GN solve (v_rcp/v_rsq/v_sin; the wave is the
//           only worker -> chain length IS wall time) + epilogue.
// Directly profilable as ONE dispatch (the r2 measurement trick), no
// inter-kernel launch gap, no workspace use.
// Moment layout:
//   0..5   : SW[ij]            = sum W_ij                (sym idx 00,01,02,11,12,22)
//   6..23  : A1[ij][c]         = sum W_ij * s_c          (6+ij*3+c)
//   24..59 : A2[ij][cd]        = sum W_ij * s_c*s_d      (24+ij*6+cd, cd sym idx)
//   60..62 : b0[i]             = sum (W g)_i
//   63..71 : B1[c][i]          = sum s_c * (W g)_i       (63+c*3+i)
// ---------------------------------------------------------------------------
__launch_bounds__(BD, 1)
__global__ void fused_kernel(const float* __restrict__ src4,
                             const float* __restrict__ trg4,
                             const float* __restrict__ wts,
                             const float* __restrict__ icov,
                             const float* __restrict__ Tinit,
                             const float* __restrict__ Tsv,
                             float* __restrict__ out, int B)
{
    const int b   = blockIdx.x;
    const int tid = threadIdx.x;

    const float* srcb = src4 + (size_t)b * 4 * NPTS;
    const float* trgb = trg4 + (size_t)b * 4 * NPTS;
    const float* wb   = wts  + (size_t)b * NPTS;
    const float* cb   = icov + (size_t)b * NPTS * 9;

    float acc[NMOM];
    #pragma unroll
    for (int k = 0; k < NMOM; ++k) acc[k] = 0.0f;

    // unroll 2: two points' loads (26) in flight per round; 2 rounds.
    #pragma unroll 2
    for (int kk = 0; kk < PPT; ++kk) {
        int n = kk * BD + tid;
        float sx = srcb[n], sy = srcb[NPTS + n], sz = srcb[2 * NPTS + n];
        float gx = trgb[n], gy = trgb[NPTS + n], gz = trgb[2 * NPTS + n];
        float w  = wb[n];
        const float* c = cb + (size_t)n * 9;
        float c0 = c[0], c3 = c[3], c4 = c[4], c6 = c[6], c7 = c[7], c8 = c[8];

        float w2 = 2.0f * w * w;
        float W[6];
        W[0] = w2 * c0;   // xx
        W[1] = w2 * c3;   // xy (lower tri, as chol reads)
        W[2] = w2 * c6;   // xz
        W[3] = w2 * c4;   // yy
        W[4] = w2 * c7;   // yz
        W[5] = w2 * c8;   // zz

        float hx = W[0] * gx + W[1] * gy + W[2] * gz;
        float hy = W[1] * gx + W[3] * gy + W[4] * gz;
        float hz = W[2] * gx + W[4] * gy + W[5] * gz;

        float sv[3] = { sx, sy, sz };
        float hv[3] = { hx, hy, hz };
        float ss[6] = { sx*sx, sx*sy, sx*sz, sy*sy, sy*sz, sz*sz };

        #pragma unroll
        for (int ij = 0; ij < 6; ++ij) {
            acc[ij] += W[ij];
            #pragma unroll
            for (int c2 = 0; c2 < 3; ++c2) acc[6 + ij * 3 + c2] += W[ij] * sv[c2];
            #pragma unroll
            for (int cd = 0; cd < 6; ++cd) acc[24 + ij * 6 + cd] += W[ij] * ss[cd];
        }
        acc[60] += hx; acc[61] += hy; acc[62] += hz;
        #pragma unroll
        for (int c2 = 0; c2 < 3; ++c2)
            #pragma unroll
            for (int i = 0; i < 3; ++i) acc[63 + c2 * 3 + i] += sv[c2] * hv[i];
    }

    // ---- Phase B: butterfly within 32-lane groups, combine 16 partials ----
    __shared__ float wsum[16][NMOM + 1];    // stride 73 -> banks spread
    __shared__ float msum[NMOM];
    const int grp = tid >> 5;               // 0..15

    #pragma unroll
    for (int k = 0; k < NMOM; ++k) {
        float v = acc[k];
        v += __shfl_xor(v, 1);
        v += __shfl_xor(v, 2);
        v += __shfl_xor(v, 4);
        v += __shfl_xor(v, 8);
        v += __shfl_xor(v, 16);
        acc[k] = v;                         // group sum in every lane
    }
    if ((tid & 31) == 0) {
        #pragma unroll
        for (int k = 0; k < NMOM; ++k) wsum[grp][k] = acc[k];
    }
    __syncthreads();
    if (tid < NMOM) {
        float s = 0.0f;
        #pragma unroll
        for (int j = 0; j < 16; ++j) s += wsum[j][tid];
        msum[tid] = s;
    }
    __syncthreads();

    if (tid != 0) return;

    // ---------------- Phase C: solve (thread 0, fast-math) ----------------
    float m[NMOM];
    #pragma unroll
    for (int k = 0; k < NMOM; ++k) m[k] = msum[k];

    float Rm[3][3], tv[3];
    #pragma unroll
    for (int i = 0; i < 3; ++i) {
        #pragma unroll
        for (int j = 0; j < 3; ++j) Rm[i][j] = Tinit[b * 16 + i * 4 + j];
        tv[i] = Tinit[b * 16 + i * 4 + 3];
    }

    const int SY[3][3] = { {0,1,2}, {1,3,4}, {2,4,5} };

    for (int it = 0; it < NITERS; ++it) {
        // C1[ij][a] = sum W_ij * p_a  (p = R s)
        float C1[6][3];
        #pragma unroll
        for (int ij = 0; ij < 6; ++ij) {
            float a0 = m[6 + ij * 3 + 0], a1 = m[6 + ij * 3 + 1], a2 = m[6 + ij * 3 + 2];
            #pragma unroll
            for (int a = 0; a < 3; ++a)
                C1[ij][a] = Rm[a][0] * a0 + Rm[a][1] * a1 + Rm[a][2] * a2;
        }
        // SM = sum W hat(p);  SWp = sum W p
        float SM[3][3], SWp[3];
        #pragma unroll
        for (int i = 0; i < 3; ++i) {
            SM[i][0] = C1[SY[i][1]][2] - C1[SY[i][2]][1];
            SM[i][1] = C1[SY[i][2]][0] - C1[SY[i][0]][2];
            SM[i][2] = C1[SY[i][0]][1] - C1[SY[i][1]][0];
            SWp[i]   = C1[SY[i][0]][0] + C1[SY[i][1]][1] + C1[SY[i][2]][2];
        }
        // P2[ab][ij] = sum p_a p_b W_ij = (R A2[ij] R^T)_{ab}
        float P2[6][6];
        #pragma unroll
        for (int ij = 0; ij < 6; ++ij) {
            float S00 = m[24 + ij * 6 + 0], S01 = m[24 + ij * 6 + 1], S02 = m[24 + ij * 6 + 2];
            float S11 = m[24 + ij * 6 + 3], S12 = m[24 + ij * 6 + 4], S22 = m[24 + ij * 6 + 5];
            float U[3][3];
            #pragma unroll
            for (int a = 0; a < 3; ++a) {
                U[a][0] = Rm[a][0] * S00 + Rm[a][1] * S01 + Rm[a][2] * S02;
                U[a][1] = Rm[a][0] * S01 + Rm[a][1] * S11 + Rm[a][2] * S12;
                U[a][2] = Rm[a][0] * S02 + Rm[a][1] * S12 + Rm[a][2] * S22;
            }
            P2[0][ij] = U[0][0]*Rm[0][0] + U[0][1]*Rm[0][1] + U[0][2]*Rm[0][2];
            P2[1][ij] = U[0][0]*Rm[1][0] + U[0][1]*Rm[1][1] + U[0][2]*Rm[1][2];
            P2[2][ij] = U[0][0]*Rm[2][0] + U[0][1]*Rm[2][1] + U[0][2]*Rm[2][2];
            P2[3][ij] = U[1][0]*Rm[1][0] + U[1][1]*Rm[1][1] + U[1][2]*Rm[1][2];
            P2[4][ij] = U[1][0]*Rm[2][0] + U[1][1]*Rm[2][1] + U[1][2]*Rm[2][2];
            P2[5][ij] = U[2][0]*Rm[2][0] + U[2][1]*Rm[2][1] + U[2][2]*Rm[2][2];
        }
        // SN = sum hat(p) W hat(p), unique entries
        float SN00 = -P2[5][3] + 2.f * P2[4][4] - P2[3][5];
        float SN01 = -P2[2][4] + P2[5][1] + P2[1][5] - P2[4][2];
        float SN02 = -P2[4][1] + P2[2][3] + P2[3][2] - P2[1][4];
        float SN11 =  2.f * P2[2][2] - P2[5][0] - P2[0][5];
        float SN12 =  P2[4][0] - P2[2][1] - P2[1][2] + P2[0][4];
        float SN22 = -P2[3][0] + 2.f * P2[1][1] - P2[0][3];

        // Su = sum W e = b0 - SWp - SW*t
        float SWt0 = m[0]*tv[0] + m[1]*tv[1] + m[2]*tv[2];
        float SWt1 = m[1]*tv[0] + m[3]*tv[1] + m[4]*tv[2];
        float SWt2 = m[2]*tv[0] + m[4]*tv[1] + m[5]*tv[2];
        float Su[3] = { m[60] - SWp[0] - SWt0,
                        m[61] - SWp[1] - SWt1,
                        m[62] - SWp[2] - SWt2 };

        // Sq = sum p x u = sum p x h - sum p x (W p) + SM^T t
        float G[3][3];
        #pragma unroll
        for (int a = 0; a < 3; ++a)
            #pragma unroll
            for (int bb = 0; bb < 3; ++bb)
                G[a][bb] = Rm[a][0]*m[63 + 0 + bb] + Rm[a][1]*m[63 + 3 + bb] + Rm[a][2]*m[63 + 6 + bb];
        float ch[3] = { G[1][2] - G[2][1], G[2][0] - G[0][2], G[0][1] - G[1][0] };
        float pw[3];
        pw[0] = P2[1][2] + P2[3][4] + P2[4][5] - P2[2][1] - P2[4][3] - P2[5][4];
        pw[1] = P2[2][0] + P2[4][1] + P2[5][2] - P2[0][2] - P2[1][4] - P2[2][5];
        pw[2] = P2[0][1] + P2[1][3] + P2[2][4] - P2[1][0] - P2[3][1] - P2[4][2];
        float Sq[3];
        #pragma unroll
        for (int i = 0; i < 3; ++i)
            Sq[i] = ch[i] - pw[i] + SM[0][i]*tv[0] + SM[1][i]*tv[1] + SM[2][i]*tv[2];

        // H (hat frame) and rhs
        float Hm[6][6];
        Hm[0][0] = m[0]; Hm[0][1] = m[1]; Hm[0][2] = m[2];
        Hm[1][1] = m[3]; Hm[1][2] = m[4]; Hm[2][2] = m[5];
        #pragma unroll
        for (int i = 0; i < 3; ++i) {
            Hm[i][3] = -SM[i][0]; Hm[i][4] = -SM[i][1]; Hm[i][5] = -SM[i][2];
        }
        Hm[3][3] = -SN00; Hm[3][4] = -SN01; Hm[3][5] = -SN02;
        Hm[4][4] = -SN11; Hm[4][5] = -SN12; Hm[5][5] = -SN22;
        #pragma unroll
        for (int i = 0; i < 6; ++i) {
            Hm[i][i] += DAMPF;
            #pragma unroll
            for (int j = 0; j < 6; ++j)
                if (j < i) Hm[i][j] = Hm[j][i];
        }
        float rhs[6] = { Su[0], Su[1], Su[2], Sq[0], Sq[1], Sq[2] };

        // Cholesky solve: invD[i] = rsqrt(pivot), multiplies only.
        float L[6][6];
        float invD[6];
        #pragma unroll
        for (int i = 0; i < 6; ++i) {
            #pragma unroll
            for (int j = 0; j < 6; ++j) {
                if (j > i) continue;
                float sum = Hm[i][j];
                #pragma unroll
                for (int k2 = 0; k2 < 6; ++k2)
                    if (k2 < j) sum -= L[i][k2] * L[j][k2];
                if (i == j) { invD[i] = frsq(sum); L[i][i] = sum * invD[i]; }
                else        L[i][j] = sum * invD[j];
            }
        }
        float z[6];
        #pragma unroll
        for (int i = 0; i < 6; ++i) {
            float sum = rhs[i];
            #pragma unroll
            for (int k2 = 0; k2 < 6; ++k2)
                if (k2 < i) sum -= L[i][k2] * z[k2];
            z[i] = sum * invD[i];
        }
        float y[6];
        #pragma unroll
        for (int i = 5; i >= 0; --i) {
            float sum = z[i];
            #pragma unroll
            for (int k2 = 0; k2 < 6; ++k2)
                if (k2 > i) sum -= L[k2][i] * y[k2];
            y[i] = sum * invD[i];
        }

        // dx = blockdiag(R,R)^T y
        float drx = Rm[0][0]*y[0] + Rm[1][0]*y[1] + Rm[2][0]*y[2];
        float dry = Rm[0][1]*y[0] + Rm[1][1]*y[1] + Rm[2][1]*y[2];
        float drz = Rm[0][2]*y[0] + Rm[1][2]*y[1] + Rm[2][2]*y[2];
        float dpx = Rm[0][0]*y[3] + Rm[1][0]*y[4] + Rm[2][0]*y[5];
        float dpy = Rm[0][1]*y[3] + Rm[1][1]*y[4] + Rm[2][1]*y[5];
        float dpz = Rm[0][2]*y[3] + Rm[1][2]*y[4] + Rm[2][2]*y[5];

        // se3_exp(dx): hardware trig + rcp (theta small here)
        float th2  = dpx*dpx + dpy*dpy + dpz*dpz;
        bool  sm   = th2 < 1e-12f;
        float th2s = sm ? 1.0f : th2;
        float th   = sqrtf(th2s);
        float ith  = frcp(th);
        float ith2 = ith * ith;
        float sth  = __sinf(th), cth = __cosf(th);
        float Ae = sm ? 1.0f : sth * ith;
        float Be = sm ? 0.5f : (1.0f - cth) * ith2;
        float Ce = sm ? (1.0f / 6.0f) : (th - sth) * ith2 * ith;
        float Rd00 = 1.0f + Be * (dpx*dpx - th2);
        float Rd01 = -Ae * dpz + Be * dpx * dpy;
        float Rd02 =  Ae * dpy + Be * dpx * dpz;
        float Rd10 =  Ae * dpz + Be * dpx * dpy;
        float Rd11 = 1.0f + Be * (dpy*dpy - th2);
        float Rd12 = -Ae * dpx + Be * dpy * dpz;
        float Rd20 = -Ae * dpy + Be * dpx * dpz;
        float Rd21 =  Ae * dpx + Be * dpy * dpz;
        float Rd22 = 1.0f + Be * (dpz*dpz - th2);
        float V00 = 1.0f + Ce * (dpx*dpx - th2);
        float V01 = -Be * dpz + Ce * dpx * dpy;
        float V02 =  Be * dpy + Ce * dpx * dpz;
        float V10 =  Be * dpz + Ce * dpx * dpy;
        float V11 = 1.0f + Ce * (dpy*dpy - th2);
        float V12 = -Be * dpx + Ce * dpy * dpz;
        float V20 = -Be * dpy + Ce * dpx * dpz;
        float V21 =  Be * dpx + Ce * dpy * dpz;
        float V22 = 1.0f + Ce * (dpz*dpz - th2);
        float tdx = V00 * drx + V01 * dry + V02 * drz;
        float tdy = V10 * drx + V11 * dry + V12 * drz;
        float tdz = V20 * drx + V21 * dry + V22 * drz;

        // T <- T * exp(dx)
        float nR[3][3];
        nR[0][0] = Rm[0][0]*Rd00 + Rm[0][1]*Rd10 + Rm[0][2]*Rd20;
        nR[0][1] = Rm[0][0]*Rd01 + Rm[0][1]*Rd11 + Rm[0][2]*Rd21;
        nR[0][2] = Rm[0][0]*Rd02 + Rm[0][1]*Rd12 + Rm[0][2]*Rd22;
        nR[1][0] = Rm[1][0]*Rd00 + Rm[1][1]*Rd10 + Rm[1][2]*Rd20;
        nR[1][1] = Rm[1][0]*Rd01 + Rm[1][1]*Rd11 + Rm[1][2]*Rd21;
        nR[1][2] = Rm[1][0]*Rd02 + Rm[1][1]*Rd12 + Rm[1][2]*Rd22;
        nR[2][0] = Rm[2][0]*Rd00 + Rm[2][1]*Rd10 + Rm[2][2]*Rd20;
        nR[2][1] = Rm[2][0]*Rd01 + Rm[2][1]*Rd11 + Rm[2][2]*Rd21;
        nR[2][2] = Rm[2][0]*Rd02 + Rm[2][1]*Rd12 + Rm[2][2]*Rd22;
        float ntx = Rm[0][0]*tdx + Rm[0][1]*tdy + Rm[0][2]*tdz + tv[0];
        float nty = Rm[1][0]*tdx + Rm[1][1]*tdy + Rm[1][2]*tdz + tv[1];
        float ntz = Rm[2][0]*tdx + Rm[2][1]*tdy + Rm[2][2]*tdz + tv[2];
        #pragma unroll
        for (int i = 0; i < 3; ++i)
            #pragma unroll
            for (int j = 0; j < 3; ++j) Rm[i][j] = nR[i][j];
        tv[0] = ntx; tv[1] = nty; tv[2] = ntz;
    }

    // epilogue: Out = inv(Tsv) * T * Tsv
    {
        float R00 = Rm[0][0], R01 = Rm[0][1], R02 = Rm[0][2];
        float R10 = Rm[1][0], R11 = Rm[1][1], R12 = Rm[1][2];
        float R20 = Rm[2][0], R21 = Rm[2][1], R22 = Rm[2][2];
        float tx = tv[0], ty = tv[1], tz = tv[2];

        float Rv00 = Tsv[0], Rv01 = Tsv[1], Rv02 = Tsv[2],  tvx = Tsv[3];
        float Rv10 = Tsv[4], Rv11 = Tsv[5], Rv12 = Tsv[6],  tvy = Tsv[7];
        float Rv20 = Tsv[8], Rv21 = Tsv[9], Rv22 = Tsv[10], tvz = Tsv[11];

        float P00 = R00*Rv00 + R01*Rv10 + R02*Rv20;
        float P01 = R00*Rv01 + R01*Rv11 + R02*Rv21;
        float P02 = R00*Rv02 + R01*Rv12 + R02*Rv22;
        float P10 = R10*Rv00 + R11*Rv10 + R12*Rv20;
        float P11 = R10*Rv01 + R11*Rv11 + R12*Rv21;
        float P12 = R10*Rv02 + R11*Rv12 + R12*Rv22;
        float P20 = R20*Rv00 + R21*Rv10 + R22*Rv20;
        float P21 = R20*Rv01 + R21*Rv11 + R22*Rv21;
        float P22 = R20*Rv02 + R21*Rv12 + R22*Rv22;
        float Ptx = R00*tvx + R01*tvy + R02*tvz + tx;
        float Pty = R10*tvx + R11*tvy + R12*tvz + ty;
        float Ptz = R20*tvx + R21*tvy + R22*tvz + tz;

        float ex = Ptx - tvx, ey = Pty - tvy, ez = Ptz - tvz;
        float* o = out + (size_t)b * 16;
        o[0]  = Rv00*P00 + Rv10*P10 + Rv20*P20;
        o[1]  = Rv00*P01 + Rv10*P11 + Rv20*P21;
        o[2]  = Rv00*P02 + Rv10*P12 + Rv20*P22;
        o[3]  = Rv00*ex  + Rv10*ey  + Rv20*ez;
        o[4]  = Rv01*P00 + Rv11*P10 + Rv21*P20;
        o[5]  = Rv01*P01 + Rv11*P11 + Rv21*P21;
        o[6]  = Rv01*P02 + Rv11*P12 + Rv21*P22;
        o[7]  = Rv01*ex  + Rv11*ey  + Rv21*ez;
        o[8]  = Rv02*P00 + Rv12*P10 + Rv22*P20;
        o[9]  = Rv02*P01 + Rv12*P11 + Rv22*P21;
        o[10] = Rv02*P02 + Rv12*P12 + Rv22*P22;
        o[11] = Rv02*ex  + Rv12*ey  + Rv22*ez;
        o[12] = 0.0f; o[13] = 0.0f; o[14] = 0.0f; o[15] = 1.0f;
    }
}

extern "C" void kernel_launch(void* const* d_in, const int* in_sizes, int n_in,
                              void* d_out, int out_size, void* d_ws, size_t ws_size,
                              hipStream_t stream)
{
    const float* src4  = (const float*)d_in[0];
    const float* trg4  = (const float*)d_in[1];
    const float* wts   = (const float*)d_in[2];
    const float* Tinit = (const float*)d_in[3];
    const float* icov  = (const float*)d_in[4];
    const float* Tsv   = (const float*)d_in[5];

    const int B = in_sizes[3] / 16;   // T_trg_src_init is (B,4,4)
    (void)d_ws; (void)ws_size;        // workspace unused

    hipLaunchKernelGGL(fused_kernel, dim3(B), dim3(BD), 0, stream,
                       src4, trg4, wts, icov, Tinit, Tsv, (float*)d_out, B);
}

// Round 6
// 103.152 us; speedup vs baseline: 1.2699x; 1.2699x over previous
//
#include <hip/hip_runtime.h>
#include <math.h>

#define NPTS   2048
#define BD1    256
#define SPLIT  2                    // blocks per batch in phase 1
#define PPB    (NPTS / SPLIT)       // 1024 points per block
#define PPT    (PPB / BD1)          // 4 points per thread
#define NMOM   72
#define NITERS 10
#define DAMPF  1e-8f

__device__ __forceinline__ float frcp(float x) { return __builtin_amdgcn_rcpf(x); }
__device__ __forceinline__ float frsq(float x) { return __builtin_amdgcn_rsqf(x); }

// ---------------------------------------------------------------------------
// Phase 1: per-batch moments (r1 structure exactly - the best measured total;
// r5's occupancy math proved this phase is only ~5-10us of the budget).
// Partials: mom[(s*NMOM + k)*B + b].
//   0..5   : SW[ij]            = sum W_ij                (sym idx 00,01,02,11,12,22)
//   6..23  : A1[ij][c]         = sum W_ij * s_c          (6+ij*3+c)
//   24..59 : A2[ij][cd]        = sum W_ij * s_c*s_d      (24+ij*6+cd, cd sym idx)
//   60..62 : b0[i]             = sum (W g)_i
//   63..71 : B1[c][i]          = sum s_c * (W g)_i       (63+c*3+i)
// ---------------------------------------------------------------------------
__launch_bounds__(BD1, 1)
__global__ void moments_kernel(const float* __restrict__ src4,
                               const float* __restrict__ trg4,
                               const float* __restrict__ wts,
                               const float* __restrict__ icov,
                               float* __restrict__ mom, int B)
{
    const int b   = blockIdx.x >> 1;        // batch
    const int s   = blockIdx.x & 1;         // split index
    const int tid = threadIdx.x;

    const float* srcb = src4 + (size_t)b * 4 * NPTS;
    const float* trgb = trg4 + (size_t)b * 4 * NPTS;
    const float* wb   = wts  + (size_t)b * NPTS;
    const float* cb   = icov + (size_t)b * NPTS * 9;

    float acc[NMOM];
    #pragma unroll
    for (int k = 0; k < NMOM; ++k) acc[k] = 0.0f;

    #pragma unroll 2
    for (int kk = 0; kk < PPT; ++kk) {
        int n = s * PPB + kk * BD1 + tid;
        float sx = srcb[n], sy = srcb[NPTS + n], sz = srcb[2 * NPTS + n];
        float gx = trgb[n], gy = trgb[NPTS + n], gz = trgb[2 * NPTS + n];
        float w  = wb[n];
        const float* c = cb + (size_t)n * 9;
        float w2 = 2.0f * w * w;
        float W[6];
        W[0] = w2 * c[0];   // xx
        W[1] = w2 * c[3];   // xy (lower tri, as chol reads)
        W[2] = w2 * c[6];   // xz
        W[3] = w2 * c[4];   // yy
        W[4] = w2 * c[7];   // yz
        W[5] = w2 * c[8];   // zz

        float hx = W[0] * gx + W[1] * gy + W[2] * gz;
        float hy = W[1] * gx + W[3] * gy + W[4] * gz;
        float hz = W[2] * gx + W[4] * gy + W[5] * gz;

        float sv[3] = { sx, sy, sz };
        float hv[3] = { hx, hy, hz };
        float ss[6] = { sx*sx, sx*sy, sx*sz, sy*sy, sy*sz, sz*sz };

        #pragma unroll
        for (int ij = 0; ij < 6; ++ij) {
            acc[ij] += W[ij];
            #pragma unroll
            for (int c2 = 0; c2 < 3; ++c2) acc[6 + ij * 3 + c2] += W[ij] * sv[c2];
            #pragma unroll
            for (int cd = 0; cd < 6; ++cd) acc[24 + ij * 6 + cd] += W[ij] * ss[cd];
        }
        acc[60] += hx; acc[61] += hy; acc[62] += hz;
        #pragma unroll
        for (int c2 = 0; c2 < 3; ++c2)
            #pragma unroll
            for (int i = 0; i < 3; ++i) acc[63 + c2 * 3 + i] += sv[c2] * hv[i];
    }

    // Block reduction via LDS transpose (two halves of 36). Row pad +1.
    __shared__ float lds[36][BD1 + 1];
    #pragma unroll
    for (int h = 0; h < 2; ++h) {
        if (h) __syncthreads();
        #pragma unroll
        for (int k = 0; k < 36; ++k) lds[k][tid] = acc[h * 36 + k];
        __syncthreads();
        if (tid < 36) {
            const float* row = lds[tid];
            float s0 = 0.f, s1 = 0.f, s2 = 0.f, s3 = 0.f;
            #pragma unroll 8
            for (int j = 0; j < BD1; j += 4) {
                s0 += row[j]; s1 += row[j + 1]; s2 += row[j + 2]; s3 += row[j + 3];
            }
            mom[((size_t)s * NMOM + h * 36 + tid) * B + b] = (s0 + s1) + (s2 + s3);
        }
    }
}

// ---------------------------------------------------------------------------
// Phase 2: one thread per batch, 64-thread blocks. __launch_bounds__(64,1)
// -> VGPR cap ~512: m[72] + P2[36] + L[36] + C1[18] + Hm-lower + locals ALL
// stay in registers (r5 proved the fused variant spilled these to scratch:
// WRITE_SIZE 688KB vs 16KB output, 45us in this phase). Fast-math
// (v_rcp/v_rsq/v_sin) replaces 27 div sequences + libm trig per iteration.
// ---------------------------------------------------------------------------
__launch_bounds__(64, 1)
__global__ void solve_kernel(const float* __restrict__ mom,
                             const float* __restrict__ Tinit,
                             const float* __restrict__ Tsv,
                             float* __restrict__ out, int B)
{
    const int b = blockIdx.x * 64 + threadIdx.x;
    if (b >= B) return;

    float m[NMOM];
    #pragma unroll
    for (int k = 0; k < NMOM; ++k)
        m[k] = mom[k * B + b] + mom[(NMOM + k) * B + b];   // sum SPLIT=2 partials

    float Rm[3][3], tv[3];
    #pragma unroll
    for (int i = 0; i < 3; ++i) {
        #pragma unroll
        for (int j = 0; j < 3; ++j) Rm[i][j] = Tinit[b * 16 + i * 4 + j];
        tv[i] = Tinit[b * 16 + i * 4 + 3];
    }

    const int SY[3][3] = { {0,1,2}, {1,3,4}, {2,4,5} };

    for (int it = 0; it < NITERS; ++it) {
        // C1[ij][a] = sum W_ij * p_a  (p = R s)
        float C1[6][3];
        #pragma unroll
        for (int ij = 0; ij < 6; ++ij) {
            float a0 = m[6 + ij * 3 + 0], a1 = m[6 + ij * 3 + 1], a2 = m[6 + ij * 3 + 2];
            #pragma unroll
            for (int a = 0; a < 3; ++a)
                C1[ij][a] = Rm[a][0] * a0 + Rm[a][1] * a1 + Rm[a][2] * a2;
        }
        // SM = sum W hat(p);  SWp = sum W p
        float SM[3][3], SWp[3];
        #pragma unroll
        for (int i = 0; i < 3; ++i) {
            SM[i][0] = C1[SY[i][1]][2] - C1[SY[i][2]][1];
            SM[i][1] = C1[SY[i][2]][0] - C1[SY[i][0]][2];
            SM[i][2] = C1[SY[i][0]][1] - C1[SY[i][1]][0];
            SWp[i]   = C1[SY[i][0]][0] + C1[SY[i][1]][1] + C1[SY[i][2]][2];
        }
        // P2[ab][ij] = sum p_a p_b W_ij = (R A2[ij] R^T)_{ab}
        float P2[6][6];
        #pragma unroll
        for (int ij = 0; ij < 6; ++ij) {
            float S00 = m[24 + ij * 6 + 0], S01 = m[24 + ij * 6 + 1], S02 = m[24 + ij * 6 + 2];
            float S11 = m[24 + ij * 6 + 3], S12 = m[24 + ij * 6 + 4], S22 = m[24 + ij * 6 + 5];
            float U[3][3];
            #pragma unroll
            for (int a = 0; a < 3; ++a) {
                U[a][0] = Rm[a][0] * S00 + Rm[a][1] * S01 + Rm[a][2] * S02;
                U[a][1] = Rm[a][0] * S01 + Rm[a][1] * S11 + Rm[a][2] * S12;
                U[a][2] = Rm[a][0] * S02 + Rm[a][1] * S12 + Rm[a][2] * S22;
            }
            P2[0][ij] = U[0][0]*Rm[0][0] + U[0][1]*Rm[0][1] + U[0][2]*Rm[0][2];
            P2[1][ij] = U[0][0]*Rm[1][0] + U[0][1]*Rm[1][1] + U[0][2]*Rm[1][2];
            P2[2][ij] = U[0][0]*Rm[2][0] + U[0][1]*Rm[2][1] + U[0][2]*Rm[2][2];
            P2[3][ij] = U[1][0]*Rm[1][0] + U[1][1]*Rm[1][1] + U[1][2]*Rm[1][2];
            P2[4][ij] = U[1][0]*Rm[2][0] + U[1][1]*Rm[2][1] + U[1][2]*Rm[2][2];
            P2[5][ij] = U[2][0]*Rm[2][0] + U[2][1]*Rm[2][1] + U[2][2]*Rm[2][2];
        }
        // SN = sum hat(p) W hat(p), unique entries
        float SN00 = -P2[5][3] + 2.f * P2[4][4] - P2[3][5];
        float SN01 = -P2[2][4] + P2[5][1] + P2[1][5] - P2[4][2];
        float SN02 = -P2[4][1] + P2[2][3] + P2[3][2] - P2[1][4];
        float SN11 =  2.f * P2[2][2] - P2[5][0] - P2[0][5];
        float SN12 =  P2[4][0] - P2[2][1] - P2[1][2] + P2[0][4];
        float SN22 = -P2[3][0] + 2.f * P2[1][1] - P2[0][3];

        // Su = sum W e = b0 - SWp - SW*t
        float SWt0 = m[0]*tv[0] + m[1]*tv[1] + m[2]*tv[2];
        float SWt1 = m[1]*tv[0] + m[3]*tv[1] + m[4]*tv[2];
        float SWt2 = m[2]*tv[0] + m[4]*tv[1] + m[5]*tv[2];
        float Su[3] = { m[60] - SWp[0] - SWt0,
                        m[61] - SWp[1] - SWt1,
                        m[62] - SWp[2] - SWt2 };

        // Sq = sum p x u
        float G[3][3];
        #pragma unroll
        for (int a = 0; a < 3; ++a)
            #pragma unroll
            for (int bb = 0; bb < 3; ++bb)
                G[a][bb] = Rm[a][0]*m[63 + 0 + bb] + Rm[a][1]*m[63 + 3 + bb] + Rm[a][2]*m[63 + 6 + bb];
        float ch[3] = { G[1][2] - G[2][1], G[2][0] - G[0][2], G[0][1] - G[1][0] };
        float pw[3];
        pw[0] = P2[1][2] + P2[3][4] + P2[4][5] - P2[2][1] - P2[4][3] - P2[5][4];
        pw[1] = P2[2][0] + P2[4][1] + P2[5][2] - P2[0][2] - P2[1][4] - P2[2][5];
        pw[2] = P2[0][1] + P2[1][3] + P2[2][4] - P2[1][0] - P2[3][1] - P2[4][2];
        float Sq[3];
        #pragma unroll
        for (int i = 0; i < 3; ++i)
            Sq[i] = ch[i] - pw[i] + SM[0][i]*tv[0] + SM[1][i]*tv[1] + SM[2][i]*tv[2];

        // H: construct LOWER triangle only (Cholesky reads j<=i only).
        float Hm[6][6];
        Hm[0][0] = m[0] + DAMPF;
        Hm[1][0] = m[1];            Hm[1][1] = m[3] + DAMPF;
        Hm[2][0] = m[2];            Hm[2][1] = m[4];            Hm[2][2] = m[5] + DAMPF;
        #pragma unroll
        for (int i = 0; i < 3; ++i) {   // lower-left block = (-SM)^T
            Hm[3][i] = -SM[i][0]; Hm[4][i] = -SM[i][1]; Hm[5][i] = -SM[i][2];
        }
        Hm[3][3] = -SN00 + DAMPF;
        Hm[4][3] = -SN01;           Hm[4][4] = -SN11 + DAMPF;
        Hm[5][3] = -SN02;           Hm[5][4] = -SN12;           Hm[5][5] = -SN22 + DAMPF;

        float rhs[6] = { Su[0], Su[1], Su[2], Sq[0], Sq[1], Sq[2] };

        // Cholesky: invD[i] = rsqrt(pivot); multiplies only, no divides.
        float L[6][6];
        float invD[6];
        #pragma unroll
        for (int i = 0; i < 6; ++i) {
            #pragma unroll
            for (int j = 0; j < 6; ++j) {
                if (j > i) continue;
                float sum = Hm[i][j];
                #pragma unroll
                for (int k2 = 0; k2 < 6; ++k2)
                    if (k2 < j) sum -= L[i][k2] * L[j][k2];
                if (i == j) { invD[i] = frsq(sum); L[i][i] = sum * invD[i]; }
                else        L[i][j] = sum * invD[j];
            }
        }
        float z[6];
        #pragma unroll
        for (int i = 0; i < 6; ++i) {
            float sum = rhs[i];
            #pragma unroll
            for (int k2 = 0; k2 < 6; ++k2)
                if (k2 < i) sum -= L[i][k2] * z[k2];
            z[i] = sum * invD[i];
        }
        float y[6];
        #pragma unroll
        for (int i = 5; i >= 0; --i) {
            float sum = z[i];
            #pragma unroll
            for (int k2 = 0; k2 < 6; ++k2)
                if (k2 > i) sum -= L[k2][i] * y[k2];
            y[i] = sum * invD[i];
        }

        // dx = blockdiag(R,R)^T y
        float drx = Rm[0][0]*y[0] + Rm[1][0]*y[1] + Rm[2][0]*y[2];
        float dry = Rm[0][1]*y[0] + Rm[1][1]*y[1] + Rm[2][1]*y[2];
        float drz = Rm[0][2]*y[0] + Rm[1][2]*y[1] + Rm[2][2]*y[2];
        float dpx = Rm[0][0]*y[3] + Rm[1][0]*y[4] + Rm[2][0]*y[5];
        float dpy = Rm[0][1]*y[3] + Rm[1][1]*y[4] + Rm[2][1]*y[5];
        float dpz = Rm[0][2]*y[3] + Rm[1][2]*y[4] + Rm[2][2]*y[5];

        // se3_exp(dx): hardware trig + rcp (theta small here)
        float th2  = dpx*dpx + dpy*dpy + dpz*dpz;
        bool  sm   = th2 < 1e-12f;
        float th2s = sm ? 1.0f : th2;
        float th   = sqrtf(th2s);
        float ith  = frcp(th);
        float ith2 = ith * ith;
        float sth  = __sinf(th), cth = __cosf(th);
        float Ae = sm ? 1.0f : sth * ith;
        float Be = sm ? 0.5f : (1.0f - cth) * ith2;
        float Ce = sm ? (1.0f / 6.0f) : (1.0f - Ae) * ith2;
        float Rd00 = 1.0f + Be * (dpx*dpx - th2);
        float Rd01 = -Ae * dpz + Be * dpx * dpy;
        float Rd02 =  Ae * dpy + Be * dpx * dpz;
        float Rd10 =  Ae * dpz + Be * dpx * dpy;
        float Rd11 = 1.0f + Be * (dpy*dpy - th2);
        float Rd12 = -Ae * dpx + Be * dpy * dpz;
        float Rd20 = -Ae * dpy + Be * dpx * dpz;
        float Rd21 =  Ae * dpx + Be * dpy * dpz;
        float Rd22 = 1.0f + Be * (dpz*dpz - th2);
        float V00 = 1.0f + Ce * (dpx*dpx - th2);
        float V01 = -Be * dpz + Ce * dpx * dpy;
        float V02 =  Be * dpy + Ce * dpx * dpz;
        float V10 =  Be * dpz + Ce * dpx * dpy;
        float V11 = 1.0f + Ce * (dpy*dpy - th2);
        float V12 = -Be * dpx + Ce * dpy * dpz;
        float V20 = -Be * dpy + Ce * dpx * dpz;
        float V21 =  Be * dpx + Ce * dpy * dpz;
        float V22 = 1.0f + Ce * (dpz*dpz - th2);
        float tdx = V00 * drx + V01 * dry + V02 * drz;
        float tdy = V10 * drx + V11 * dry + V12 * drz;
        float tdz = V20 * drx + V21 * dry + V22 * drz;

        // T <- T * exp(dx)
        float nR[3][3];
        nR[0][0] = Rm[0][0]*Rd00 + Rm[0][1]*Rd10 + Rm[0][2]*Rd20;
        nR[0][1] = Rm[0][0]*Rd01 + Rm[0][1]*Rd11 + Rm[0][2]*Rd21;
        nR[0][2] = Rm[0][0]*Rd02 + Rm[0][1]*Rd12 + Rm[0][2]*Rd22;
        nR[1][0] = Rm[1][0]*Rd00 + Rm[1][1]*Rd10 + Rm[1][2]*Rd20;
        nR[1][1] = Rm[1][0]*Rd01 + Rm[1][1]*Rd11 + Rm[1][2]*Rd21;
        nR[1][2] = Rm[1][0]*Rd02 + Rm[1][1]*Rd12 + Rm[1][2]*Rd22;
        nR[2][0] = Rm[2][0]*Rd00 + Rm[2][1]*Rd10 + Rm[2][2]*Rd20;
        nR[2][1] = Rm[2][0]*Rd01 + Rm[2][1]*Rd11 + Rm[2][2]*Rd21;
        nR[2][2] = Rm[2][0]*Rd02 + Rm[2][1]*Rd12 + Rm[2][2]*Rd22;
        float ntx = Rm[0][0]*tdx + Rm[0][1]*tdy + Rm[0][2]*tdz + tv[0];
        float nty = Rm[1][0]*tdx + Rm[1][1]*tdy + Rm[1][2]*tdz + tv[1];
        float ntz = Rm[2][0]*tdx + Rm[2][1]*tdy + Rm[2][2]*tdz + tv[2];
        #pragma unroll
        for (int i = 0; i < 3; ++i)
            #pragma unroll
            for (int j = 0; j < 3; ++j) Rm[i][j] = nR[i][j];
        tv[0] = ntx; tv[1] = nty; tv[2] = ntz;
    }

    // epilogue: Out = inv(Tsv) * T * Tsv
    {
        float R00 = Rm[0][0], R01 = Rm[0][1], R02 = Rm[0][2];
        float R10 = Rm[1][0], R11 = Rm[1][1], R12 = Rm[1][2];
        float R20 = Rm[2][0], R21 = Rm[2][1], R22 = Rm[2][2];
        float tx = tv[0], ty = tv[1], tz = tv[2];

        float Rv00 = Tsv[0], Rv01 = Tsv[1], Rv02 = Tsv[2],  tvx = Tsv[3];
        float Rv10 = Tsv[4], Rv11 = Tsv[5], Rv12 = Tsv[6],  tvy = Tsv[7];
        float Rv20 = Tsv[8], Rv21 = Tsv[9], Rv22 = Tsv[10], tvz = Tsv[11];

        float P00 = R00*Rv00 + R01*Rv10 + R02*Rv20;
        float P01 = R00*Rv01 + R01*Rv11 + R02*Rv21;
        float P02 = R00*Rv02 + R01*Rv12 + R02*Rv22;
        float P10 = R10*Rv00 + R11*Rv10 + R12*Rv20;
        float P11 = R10*Rv01 + R11*Rv11 + R12*Rv21;
        float P12 = R10*Rv02 + R11*Rv12 + R12*Rv22;
        float P20 = R20*Rv00 + R21*Rv10 + R22*Rv20;
        float P21 = R20*Rv01 + R21*Rv11 + R22*Rv21;
        float P22 = R20*Rv02 + R21*Rv12 + R22*Rv22;
        float Ptx = R00*tvx + R01*tvy + R02*tvz + tx;
        float Pty = R10*tvx + R11*tvy + R12*tvz + ty;
        float Ptz = R20*tvx + R21*tvy + R22*tvz + tz;

        float ex = Ptx - tvx, ey = Pty - tvy, ez = Ptz - tvz;
        float* o = out + (size_t)b * 16;
        o[0]  = Rv00*P00 + Rv10*P10 + Rv20*P20;
        o[1]  = Rv00*P01 + Rv10*P11 + Rv20*P21;
        o[2]  = Rv00*P02 + Rv10*P12 + Rv20*P22;
        o[3]  = Rv00*ex  + Rv10*ey  + Rv20*ez;
        o[4]  = Rv01*P00 + Rv11*P10 + Rv21*P20;
        o[5]  = Rv01*P01 + Rv11*P11 + Rv21*P21;
        o[6]  = Rv01*P02 + Rv11*P12 + Rv21*P22;
        o[7]  = Rv01*ex  + Rv11*ey  + Rv21*ez;
        o[8]  = Rv02*P00 + Rv12*P10 + Rv22*P20;
        o[9]  = Rv02*P01 + Rv12*P11 + Rv22*P21;
        o[10] = Rv02*P02 + Rv12*P12 + Rv22*P22;
        o[11] = Rv02*ex  + Rv12*ey  + Rv22*ez;
        o[12] = 0.0f; o[13] = 0.0f; o[14] = 0.0f; o[15] = 1.0f;
    }
}

extern "C" void kernel_launch(void* const* d_in, const int* in_sizes, int n_in,
                              void* d_out, int out_size, void* d_ws, size_t ws_size,
                              hipStream_t stream)
{
    const float* src4  = (const float*)d_in[0];
    const float* trg4  = (const float*)d_in[1];
    const float* wts   = (const float*)d_in[2];
    const float* Tinit = (const float*)d_in[3];
    const float* icov  = (const float*)d_in[4];
    const float* Tsv   = (const float*)d_in[5];

    const int B = in_sizes[3] / 16;   // T_trg_src_init is (B,4,4)
    float* mom = (float*)d_ws;        // SPLIT*72*B floats

    hipLaunchKernelGGL(moments_kernel, dim3(B * SPLIT), dim3(BD1), 0, stream,
                       src4, trg4, wts, icov, mom, B);
    hipLaunchKernelGGL(solve_kernel, dim3((B + 63) / 64), dim3(64), 0, stream,
                       mom, Tinit, Tsv, (float*)d_out, B);
}